// Round 1
// 1003.663 us; speedup vs baseline: 1.4823x; 1.4823x over previous
//
#include <hip/hip_runtime.h>

// GCN via dst-range binning + per-bin LDS accumulation (no global CSR, no per-edge
// global atomics).
// Round-2 finding: k_fill's 6.4M scattered atomics + random 4B csr writes cost 590us
// at 9% HBM BW (385MB writes for 25.6MB payload, ~64B/store amplification).
// => bin edges by dst>>7 (782 bins of 128 nodes). Binning uses one reservation atomic
//    per (block,bin) (~153K total); per-block runs are contiguous so write-back is
//    ~payload-sized. Aggregation = LDS float atomics per bin; deg also per-bin LDS.
// Norm factorization unchanged: sum_e h[src]*dinv[src]*dinv[dst] = dinv[dst]*sum(h*dinv)[src].

#define RSH 7            // log2(nodes per bin)
#define RNB 128          // nodes per bin
#define NBMAX 1024       // max bins supported (N <= 131072)
#define CAPB 8960        // per-bin edge capacity: mean E*128/N = 8192, sigma ~90 => +8.5 sigma
#define CHB 32768        // edges per binning block

__global__ void k_init(int* __restrict__ gcur, int B) {
    int t = blockIdx.x * blockDim.x + threadIdx.x;
    if (t < B) gcur[t] = t * CAPB;
}

// Chunked binning: LDS histogram -> one global reservation atomic per (block,bin) ->
// scatter packed edges. Per-(block,bin) runs are contiguous (~21 entries), so the
// write frontier (a few lines per bin, owned by this block) fills lines before eviction.
__global__ void __launch_bounds__(512) k_bin(const int* __restrict__ src, const int* __restrict__ dst,
                                             int* __restrict__ gcur, int* __restrict__ binned,
                                             int E, int B) {
    __shared__ int hist[NBMAX];
    __shared__ int base[NBMAX];
    int tid = threadIdx.x;
    int e0 = blockIdx.x * CHB;
    int n = E - e0; if (n > CHB) n = CHB;
    for (int t = tid; t < B; t += 512) hist[t] = 0;
    __syncthreads();
    for (int k = tid; k < n; k += 512) atomicAdd(&hist[dst[e0 + k] >> RSH], 1);
    __syncthreads();
    for (int t = tid; t < B; t += 512) {
        int h = hist[t];
        base[t] = h ? atomicAdd(&gcur[t], h) : 0;
        hist[t] = 0;  // reuse as local cursor
    }
    __syncthreads();
    for (int k = tid; k < n; k += 512) {
        int d = dst[e0 + k], s = src[e0 + k];
        int b = d >> RSH;
        int pos = base[b] + atomicAdd(&hist[b], 1);
        if (pos < (b + 1) * CAPB)  // overflow guard (deterministic input, 8.5-sigma slack)
            binned[pos] = ((d & (RNB - 1)) << 17) | s;  // src < 2^17
    }
}

// Per-bin: deg via LDS int histogram -> dinv, xs = x*dinv (replaces k_count + k_scan).
__global__ void __launch_bounds__(256) k_deg(const int* __restrict__ gcur, const int* __restrict__ binned,
                                             const float* __restrict__ x, float* __restrict__ dinv,
                                             float* __restrict__ xs, int N) {
    __shared__ int deg[RNB];
    int tid = threadIdx.x, b = blockIdx.x;
    if (tid < RNB) deg[tid] = 0;
    __syncthreads();
    int beg = b * CAPB;
    int end = gcur[b]; int cap = beg + CAPB; if (end > cap) end = cap;
    for (int e = beg + tid; e < end; e += 256) atomicAdd(&deg[binned[e] >> 17], 1);
    __syncthreads();
    int i = b * RNB + tid;
    if (tid < RNB && i < N) {
        float dv = rsqrtf((float)deg[tid] + 1.0f);
        dinv[i] = dv;
        float2 v = *reinterpret_cast<const float2*>(x + 2 * (size_t)i);
        float2 o; o.x = v.x * dv; o.y = v.y * dv;
        *reinterpret_cast<float2*>(xs + 2 * (size_t)i) = o;
    }
}

// Per-bin layer 1: LDS-atomic aggregate of xs (2 feats), then per-node
// z -> h1=relu(z@W1+b1) -> h2lin=h1@W2, h2s=h2lin*dinv.
__global__ void __launch_bounds__(256) k_l1(const int* __restrict__ gcur, const int* __restrict__ binned,
                                            const float* __restrict__ xs, const float* __restrict__ x,
                                            const float* __restrict__ dinv,
                                            const float* __restrict__ W1, const float* __restrict__ b1,
                                            const float* __restrict__ W2,
                                            float* __restrict__ h2lin, float* __restrict__ h2s, int N) {
    __shared__ float a0[RNB], a1[RNB];
    int tid = threadIdx.x, b = blockIdx.x;
    if (tid < RNB) { a0[tid] = 0.f; a1[tid] = 0.f; }
    __syncthreads();
    int beg = b * CAPB;
    int end = gcur[b]; int cap = beg + CAPB; if (end > cap) end = cap;
    for (int e = beg + tid; e < end; e += 256) {
        int p = binned[e];
        int s = p & 0x1FFFF, dl = p >> 17;
        float2 v = *reinterpret_cast<const float2*>(xs + 2 * (size_t)s);  // L2-resident (800KB)
        atomicAdd(&a0[dl], v.x);
        atomicAdd(&a1[dl], v.y);
    }
    __syncthreads();
    int i = b * RNB + tid;
    if (tid < RNB && i < N) {
        float dv = dinv[i], dv2 = dv * dv;
        float z0 = dv * a0[tid] + x[2 * (size_t)i] * dv2;
        float z1 = dv * a1[tid] + x[2 * (size_t)i + 1] * dv2;
        float acc[8];
#pragma unroll
        for (int g = 0; g < 8; ++g) acc[g] = 0.f;
#pragma unroll
        for (int f = 0; f < 16; ++f) {
            float h = fmaf(z0, W1[f], fmaf(z1, W1[16 + f], b1[f]));  // W1 [2,16] row-major
            h = fmaxf(h, 0.f);
#pragma unroll
            for (int g = 0; g < 8; ++g) acc[g] = fmaf(h, W2[f * 8 + g], acc[g]);
        }
        float4* o = reinterpret_cast<float4*>(h2lin + 8 * (size_t)i);
        o[0] = make_float4(acc[0], acc[1], acc[2], acc[3]);
        o[1] = make_float4(acc[4], acc[5], acc[6], acc[7]);
        float4* o2 = reinterpret_cast<float4*>(h2s + 8 * (size_t)i);
        o2[0] = make_float4(acc[0] * dv, acc[1] * dv, acc[2] * dv, acc[3] * dv);
        o2[1] = make_float4(acc[4] * dv, acc[5] * dv, acc[6] * dv, acc[7] * dv);
    }
}

// Per-bin layer 2: LDS-atomic aggregate of h2s (8 feats, pad 9 to break the x8-stride
// bank pattern), then zfin = dinv*agg + h2lin*dinv^2 + b2.
__global__ void __launch_bounds__(256) k_l2(const int* __restrict__ gcur, const int* __restrict__ binned,
                                            const float* __restrict__ h2s, const float* __restrict__ h2lin,
                                            const float* __restrict__ dinv, const float* __restrict__ b2,
                                            float* __restrict__ zfin, int N) {
    __shared__ float acc[RNB][9];
    int tid = threadIdx.x, b = blockIdx.x;
    for (int t = tid; t < RNB * 9; t += 256) ((float*)acc)[t] = 0.f;
    __syncthreads();
    int beg = b * CAPB;
    int end = gcur[b]; int cap = beg + CAPB; if (end > cap) end = cap;
    for (int e = beg + tid; e < end; e += 256) {
        int p = binned[e];
        int s = p & 0x1FFFF, dl = p >> 17;
        const float4* hp = reinterpret_cast<const float4*>(h2s + 8 * (size_t)s);  // L2-resident (3.2MB)
        float4 u = hp[0], w = hp[1];
        atomicAdd(&acc[dl][0], u.x); atomicAdd(&acc[dl][1], u.y);
        atomicAdd(&acc[dl][2], u.z); atomicAdd(&acc[dl][3], u.w);
        atomicAdd(&acc[dl][4], w.x); atomicAdd(&acc[dl][5], w.y);
        atomicAdd(&acc[dl][6], w.z); atomicAdd(&acc[dl][7], w.w);
    }
    __syncthreads();
    int i = b * RNB + tid;
    if (tid < RNB && i < N) {
        float dv = dinv[i], dv2 = dv * dv;
        const float4* hl = reinterpret_cast<const float4*>(h2lin + 8 * (size_t)i);
        float4 h0 = hl[0], h1v = hl[1];
        float4 r0, r1;
        r0.x = dv * acc[tid][0] + h0.x * dv2 + b2[0];
        r0.y = dv * acc[tid][1] + h0.y * dv2 + b2[1];
        r0.z = dv * acc[tid][2] + h0.z * dv2 + b2[2];
        r0.w = dv * acc[tid][3] + h0.w * dv2 + b2[3];
        r1.x = dv * acc[tid][4] + h1v.x * dv2 + b2[4];
        r1.y = dv * acc[tid][5] + h1v.y * dv2 + b2[5];
        r1.z = dv * acc[tid][6] + h1v.z * dv2 + b2[6];
        r1.w = dv * acc[tid][7] + h1v.w * dv2 + b2[7];
        float4* o = reinterpret_cast<float4*>(zfin + 8 * (size_t)i);
        o[0] = r0; o[1] = r1;
    }
}

// out[i,:] = zfin[i] @ Wfc + bfc. 8 nodes/block; thread t owns cols 4t..4t+3.
// Near the 400MB write roofline; unchanged.
__global__ void k_final(const float* __restrict__ zfin, const float* __restrict__ Wfc,
                        const float* __restrict__ bfc, float* __restrict__ out, int N, int C) {
    __shared__ float sh[64];
    int i0 = blockIdx.x * 8;
    int t = threadIdx.x;
    if (t < 64) {
        int i = i0 + (t >> 3);
        sh[t] = (i < N) ? zfin[8 * (size_t)i + (t & 7)] : 0.f;
    }
    __syncthreads();
    int c4 = t * 4;
    if (c4 + 4 <= C) {
        float4 w[8];
#pragma unroll
        for (int f = 0; f < 8; ++f)
            w[f] = *reinterpret_cast<const float4*>(Wfc + (size_t)f * C + c4);
        float4 bias = *reinterpret_cast<const float4*>(bfc + c4);
#pragma unroll 1
        for (int k = 0; k < 8; ++k) {
            int i = i0 + k;
            if (i >= N) break;
            float4 acc = bias;
#pragma unroll
            for (int f = 0; f < 8; ++f) {
                float hv = sh[k * 8 + f];
                acc.x = fmaf(hv, w[f].x, acc.x);
                acc.y = fmaf(hv, w[f].y, acc.y);
                acc.z = fmaf(hv, w[f].z, acc.z);
                acc.w = fmaf(hv, w[f].w, acc.w);
            }
            *reinterpret_cast<float4*>(out + (size_t)i * C + c4) = acc;
        }
    }
}

extern "C" void kernel_launch(void* const* d_in, const int* in_sizes, int n_in,
                              void* d_out, int out_size, void* d_ws, size_t ws_size,
                              hipStream_t stream) {
    const float* x   = (const float*)d_in[0];
    const int*   ei  = (const int*)d_in[1];
    const float* W1  = (const float*)d_in[2];
    const float* b1  = (const float*)d_in[3];
    const float* W2  = (const float*)d_in[4];
    const float* b2  = (const float*)d_in[5];
    const float* Wfc = (const float*)d_in[6];
    const float* bfc = (const float*)d_in[7];
    float* out = (float*)d_out;

    const int N = in_sizes[0] / 2;  // x is [N,2]
    const int E = in_sizes[1] / 2;  // edge_index is [2,E]
    const int C = in_sizes[7];      // bfc is [C]
    const int* src = ei;
    const int* dst = ei + E;

    const int B = (N + RNB - 1) >> RSH;  // bins (782 for N=100000)

    // ws layout (64B-aligned regions)
    size_t NP = (size_t)((N + 16) & ~15);
    int* gcur   = (int*)d_ws;                         // [NBMAX]
    int* binned = gcur + NBMAX;                       // [B*CAPB] packed (dl<<17)|src
    float* fb    = (float*)(binned + (size_t)B * CAPB);
    float* dinv  = fb;              // [NP]
    float* xs    = dinv + NP;       // [2*NP]
    float* h2lin = xs + 2 * NP;     // [8*NP]
    float* h2s   = h2lin + 8 * NP;  // [8*NP]
    float* zfin  = h2s + 8 * NP;    // [8*NP]

    k_init<<<(B + 255) / 256, 256, 0, stream>>>(gcur, B);
    k_bin<<<(E + CHB - 1) / CHB, 512, 0, stream>>>(src, dst, gcur, binned, E, B);
    k_deg<<<B, 256, 0, stream>>>(gcur, binned, x, dinv, xs, N);
    k_l1 <<<B, 256, 0, stream>>>(gcur, binned, xs, x, dinv, W1, b1, W2, h2lin, h2s, N);
    k_l2 <<<B, 256, 0, stream>>>(gcur, binned, h2s, h2lin, dinv, b2, zfin, N);
    k_final<<<(N + 7) / 8, 256, 0, stream>>>(zfin, Wfc, bfc, out, N, C);
}

// Round 2
// 717.231 us; speedup vs baseline: 2.0742x; 1.3994x over previous
//
#include <hip/hip_runtime.h>

// GCN via dst-range binning + bin-local counting sort -> CSR gather (zero aggregation
// atomics).
// Round-2 finding: per-edge LDS float atomics serialize (k_l2: 51.2M ds_add = 338us
// with ALL pipes idle: 1.2% HBM, 0.4% VALU). LDS atomics ~4cyc each under same-address
// collision => aggregate by GATHER, not scatter.
// Pipeline: bin edges by dst>>7 (packed (dl<<17)|src) -> per-bin LDS stage + histogram
// + wave-scan + in-place counting sort (binned becomes node-sorted CSR, offS/offE per
// node) -> wave-per-node gather for both layers (no atomics) -> final GEMM.
// Norm factorization: sum_e h[src]*dinv[src]*dinv[dst] = dinv[dst]*sum(h*dinv)[src].

#define RSH 7            // log2(nodes per bin)
#define RNB 128          // nodes per bin
#define NBMAX 1024       // max bins supported (N <= 131072)
#define CAPB 8960        // per-bin edge capacity: mean E*128/N = 8192, sigma ~90 => +8.5 sigma
#define CHB 16384        // edges per binning block (391 blocks > 256 CUs)

__global__ void k_init(int* __restrict__ gcur, int B) {
    int t = blockIdx.x * blockDim.x + threadIdx.x;
    if (t < B) gcur[t] = t * CAPB;
}

// Chunked binning: LDS histogram -> one global reservation atomic per (block,bin) ->
// scatter packed edges. Per-(block,bin) runs are contiguous so the write frontier
// (a few lines per bin, block-owned) fills cachelines before eviction.
__global__ void __launch_bounds__(512) k_bin(const int* __restrict__ src, const int* __restrict__ dst,
                                             int* __restrict__ gcur, int* __restrict__ binned,
                                             int E, int B) {
    __shared__ int hist[NBMAX];
    __shared__ int base[NBMAX];
    int tid = threadIdx.x;
    int e0 = blockIdx.x * CHB;
    int n = E - e0; if (n > CHB) n = CHB;
    for (int t = tid; t < B; t += 512) hist[t] = 0;
    __syncthreads();
    for (int k = tid; k < n; k += 512) atomicAdd(&hist[dst[e0 + k] >> RSH], 1);
    __syncthreads();
    for (int t = tid; t < B; t += 512) {
        int h = hist[t];
        base[t] = h ? atomicAdd(&gcur[t], h) : 0;
        hist[t] = 0;  // reuse as local cursor
    }
    __syncthreads();
    for (int k = tid; k < n; k += 512) {
        int d = dst[e0 + k], s = src[e0 + k];
        int b = d >> RSH;
        int pos = base[b] + atomicAdd(&hist[b], 1);
        if (pos < (b + 1) * CAPB)  // overflow guard (deterministic input, 8.5-sigma slack)
            binned[pos] = ((d & (RNB - 1)) << 17) | s;  // src < 2^17
    }
}

// Per-bin fused: stage bin edges to LDS -> deg histogram -> wave-shuffle exclusive scan
// -> offS/offE + dinv + xs=x*dinv -> in-place counting sort (binned becomes src-only,
// node-sorted CSR). Only int LDS atomics (1 hist + 1 cursor per edge).
__global__ void __launch_bounds__(256) k_degsort(const int* __restrict__ gcur, int* __restrict__ binned,
                                                 const float* __restrict__ x, float* __restrict__ dinv,
                                                 float* __restrict__ xs, int* __restrict__ offS,
                                                 int* __restrict__ offE, int N) {
    __shared__ int buf[CAPB];
    __shared__ int deg[RNB];
    __shared__ int cur[RNB];
    __shared__ int wtot[2];
    int tid = threadIdx.x, b = blockIdx.x;
    int beg = b * CAPB;
    int end = gcur[b]; int cap = beg + CAPB; if (end > cap) end = cap;
    int cnt = end - beg;
    if (tid < RNB) deg[tid] = 0;
    __syncthreads();
    for (int k = tid; k < cnt; k += 256) {
        int p = binned[beg + k];
        buf[k] = p;
        atomicAdd(&deg[p >> 17], 1);
    }
    __syncthreads();
    int lane = tid & 63;
    int v = 0, incl = 0;
    if (tid < RNB) {
        v = deg[tid];
        incl = v;
#pragma unroll
        for (int d = 1; d < 64; d <<= 1) {
            int t = __shfl_up(incl, d);
            if (lane >= d) incl += t;
        }
        if (lane == 63) wtot[tid >> 6] = incl;
    }
    __syncthreads();
    if (tid < RNB) {
        int excl = ((tid >= 64) ? wtot[0] : 0) + incl - v;
        cur[tid] = beg + excl;
        int i = b * RNB + tid;
        if (i < N) {
            offS[i] = beg + excl;
            offE[i] = beg + excl + v;
            float dv = rsqrtf((float)v + 1.0f);
            dinv[i] = dv;
            float2 xv = *reinterpret_cast<const float2*>(x + 2 * (size_t)i);
            float2 o; o.x = xv.x * dv; o.y = xv.y * dv;
            *reinterpret_cast<float2*>(xs + 2 * (size_t)i) = o;
        }
    }
    __syncthreads();
    for (int k = tid; k < cnt; k += 256) {
        int p = buf[k];
        int pos = atomicAdd(&cur[p >> 17], 1);
        binned[pos] = p & 0x1FFFF;  // sorted, src-only (all global reads staged already)
    }
}

// Wave-per-node gather: agg of xs (2 feats) -> z -> h1=relu(z@W1+b1) -> h2lin=h1@W2,
// h2s=h2lin*dinv. xs is 800KB => L2-resident gathers.
__global__ void k_l1(const int* __restrict__ offS, const int* __restrict__ offE,
                     const int* __restrict__ csr, const float* __restrict__ xs,
                     const float* __restrict__ x, const float* __restrict__ dinv,
                     const float* __restrict__ W1, const float* __restrict__ b1,
                     const float* __restrict__ W2,
                     float* __restrict__ h2lin, float* __restrict__ h2s, int N) {
    int gid = blockIdx.x * blockDim.x + threadIdx.x;
    int i = gid >> 6, lane = gid & 63;
    if (i >= N) return;
    int beg = offS[i], end = offE[i];
    float a0 = 0.f, a1 = 0.f;
    for (int e = beg + lane; e < end; e += 64) {
        int s = csr[e];
        float2 v = *reinterpret_cast<const float2*>(xs + 2 * (size_t)s);
        a0 += v.x; a1 += v.y;
    }
#pragma unroll
    for (int d = 32; d > 0; d >>= 1) { a0 += __shfl_xor(a0, d); a1 += __shfl_xor(a1, d); }
    if (lane == 0) {
        float dv = dinv[i], dv2 = dv * dv;
        float z0 = dv * a0 + x[2 * (size_t)i] * dv2;
        float z1 = dv * a1 + x[2 * (size_t)i + 1] * dv2;
        float acc[8];
#pragma unroll
        for (int g = 0; g < 8; ++g) acc[g] = 0.f;
#pragma unroll
        for (int f = 0; f < 16; ++f) {
            float h = fmaf(z0, W1[f], fmaf(z1, W1[16 + f], b1[f]));  // W1 [2,16] row-major
            h = fmaxf(h, 0.f);
#pragma unroll
            for (int g = 0; g < 8; ++g) acc[g] = fmaf(h, W2[f * 8 + g], acc[g]);
        }
        float4* o = reinterpret_cast<float4*>(h2lin + 8 * (size_t)i);
        o[0] = make_float4(acc[0], acc[1], acc[2], acc[3]);
        o[1] = make_float4(acc[4], acc[5], acc[6], acc[7]);
        float4* o2 = reinterpret_cast<float4*>(h2s + 8 * (size_t)i);
        o2[0] = make_float4(acc[0] * dv, acc[1] * dv, acc[2] * dv, acc[3] * dv);
        o2[1] = make_float4(acc[4] * dv, acc[5] * dv, acc[6] * dv, acc[7] * dv);
    }
}

// Wave-per-node gather: agg of h2s (8 feats, 3.2MB L2-resident) + self-loop + b2 -> zfin.
__global__ void k_l2(const int* __restrict__ offS, const int* __restrict__ offE,
                     const int* __restrict__ csr, const float* __restrict__ h2s,
                     const float* __restrict__ h2lin, const float* __restrict__ dinv,
                     const float* __restrict__ b2, float* __restrict__ zfin, int N) {
    int gid = blockIdx.x * blockDim.x + threadIdx.x;
    int i = gid >> 6, lane = gid & 63;
    if (i >= N) return;
    int beg = offS[i], end = offE[i];
    float a[8];
#pragma unroll
    for (int g = 0; g < 8; ++g) a[g] = 0.f;
    for (int e = beg + lane; e < end; e += 64) {
        int s = csr[e];
        const float4* p = reinterpret_cast<const float4*>(h2s + 8 * (size_t)s);
        float4 u = p[0], w = p[1];
        a[0] += u.x; a[1] += u.y; a[2] += u.z; a[3] += u.w;
        a[4] += w.x; a[5] += w.y; a[6] += w.z; a[7] += w.w;
    }
#pragma unroll
    for (int g = 0; g < 8; ++g) {
#pragma unroll
        for (int d = 32; d > 0; d >>= 1) a[g] += __shfl_xor(a[g], d);
    }
    if (lane == 0) {
        float dv = dinv[i], dv2 = dv * dv;
        const float4* hl = reinterpret_cast<const float4*>(h2lin + 8 * (size_t)i);
        float4 h0 = hl[0], h1v = hl[1];
        float4 r0, r1;
        r0.x = dv * a[0] + h0.x * dv2 + b2[0];
        r0.y = dv * a[1] + h0.y * dv2 + b2[1];
        r0.z = dv * a[2] + h0.z * dv2 + b2[2];
        r0.w = dv * a[3] + h0.w * dv2 + b2[3];
        r1.x = dv * a[4] + h1v.x * dv2 + b2[4];
        r1.y = dv * a[5] + h1v.y * dv2 + b2[5];
        r1.z = dv * a[6] + h1v.z * dv2 + b2[6];
        r1.w = dv * a[7] + h1v.w * dv2 + b2[7];
        float4* o = reinterpret_cast<float4*>(zfin + 8 * (size_t)i);
        o[0] = r0; o[1] = r1;
    }
}

// out[i,:] = zfin[i] @ Wfc + bfc. 8 nodes/block; thread t owns cols 4t..4t+3.
// Near the 400MB write roofline; unchanged.
__global__ void k_final(const float* __restrict__ zfin, const float* __restrict__ Wfc,
                        const float* __restrict__ bfc, float* __restrict__ out, int N, int C) {
    __shared__ float sh[64];
    int i0 = blockIdx.x * 8;
    int t = threadIdx.x;
    if (t < 64) {
        int i = i0 + (t >> 3);
        sh[t] = (i < N) ? zfin[8 * (size_t)i + (t & 7)] : 0.f;
    }
    __syncthreads();
    int c4 = t * 4;
    if (c4 + 4 <= C) {
        float4 w[8];
#pragma unroll
        for (int f = 0; f < 8; ++f)
            w[f] = *reinterpret_cast<const float4*>(Wfc + (size_t)f * C + c4);
        float4 bias = *reinterpret_cast<const float4*>(bfc + c4);
#pragma unroll 1
        for (int k = 0; k < 8; ++k) {
            int i = i0 + k;
            if (i >= N) break;
            float4 acc = bias;
#pragma unroll
            for (int f = 0; f < 8; ++f) {
                float hv = sh[k * 8 + f];
                acc.x = fmaf(hv, w[f].x, acc.x);
                acc.y = fmaf(hv, w[f].y, acc.y);
                acc.z = fmaf(hv, w[f].z, acc.z);
                acc.w = fmaf(hv, w[f].w, acc.w);
            }
            *reinterpret_cast<float4*>(out + (size_t)i * C + c4) = acc;
        }
    }
}

extern "C" void kernel_launch(void* const* d_in, const int* in_sizes, int n_in,
                              void* d_out, int out_size, void* d_ws, size_t ws_size,
                              hipStream_t stream) {
    const float* x   = (const float*)d_in[0];
    const int*   ei  = (const int*)d_in[1];
    const float* W1  = (const float*)d_in[2];
    const float* b1  = (const float*)d_in[3];
    const float* W2  = (const float*)d_in[4];
    const float* b2  = (const float*)d_in[5];
    const float* Wfc = (const float*)d_in[6];
    const float* bfc = (const float*)d_in[7];
    float* out = (float*)d_out;

    const int N = in_sizes[0] / 2;  // x is [N,2]
    const int E = in_sizes[1] / 2;  // edge_index is [2,E]
    const int C = in_sizes[7];      // bfc is [C]
    const int* src = ei;
    const int* dst = ei + E;

    const int B = (N + RNB - 1) >> RSH;  // bins (782 for N=100000)

    // ws layout (64B-aligned regions)
    size_t NP = (size_t)((N + 16) & ~15);
    int* gcur   = (int*)d_ws;                         // [NBMAX]
    int* binned = gcur + NBMAX;                       // [B*CAPB]; packed, then sorted src-only
    int* offS   = binned + (size_t)B * CAPB;          // [NP]
    int* offE   = offS + NP;                          // [NP]
    float* fb    = (float*)(offE + NP);
    float* dinv  = fb;              // [NP]
    float* xs    = dinv + NP;       // [2*NP]
    float* h2lin = xs + 2 * NP;     // [8*NP]
    float* h2s   = h2lin + 8 * NP;  // [8*NP]
    float* zfin  = h2s + 8 * NP;    // [8*NP]

    k_init<<<(B + 255) / 256, 256, 0, stream>>>(gcur, B);
    k_bin<<<(E + CHB - 1) / CHB, 512, 0, stream>>>(src, dst, gcur, binned, E, B);
    k_degsort<<<B, 256, 0, stream>>>(gcur, binned, x, dinv, xs, offS, offE, N);
    {
        long long tot = (long long)N * 64;  // one wave per node
        k_l1<<<(int)((tot + 255) / 256), 256, 0, stream>>>(offS, offE, binned, xs, x, dinv,
                                                           W1, b1, W2, h2lin, h2s, N);
        k_l2<<<(int)((tot + 255) / 256), 256, 0, stream>>>(offS, offE, binned, h2s, h2lin,
                                                           dinv, b2, zfin, N);
    }
    k_final<<<(N + 7) / 8, 256, 0, stream>>>(zfin, Wfc, bfc, out, N, C);
}

// Round 4
// 691.136 us; speedup vs baseline: 2.1525x; 1.0378x over previous
//
#include <hip/hip_runtime.h>

// GCN via dst-range binning + bin-local counting sort -> CSR gather (zero aggregation
// atomics).
// Round-4: round-3 bench died in infra ("container failed twice", no profile). Same
// design resubmitted with the one risky construct removed: k_degsort now uses a SINGLE
// CAPB LDS buffer (~37KB, 4 blocks/CU) — histogram on 1st global read (L2-warm),
// scatter-sort into LDS on 2nd read, coalesced writeback. k_l2+k_final stay fused
// (zfin 3.2MB roundtrip + one launch eliminated).
// Pipeline: bin edges by dst>>7 (packed (dl<<17)|src) -> per-bin histogram + wave-scan
// + LDS counting sort + coalesced writeback (binned becomes node-sorted CSR with
// offS/offE) -> wave-per-node gather layer1 -> fused gather layer2 + 1000-col GEMM.
// Norm factorization: sum_e h[src]*dinv[src]*dinv[dst] = dinv[dst]*sum(h*dinv)[src].

#define RSH 7            // log2(nodes per bin)
#define RNB 128          // nodes per bin
#define NBMAX 1024       // max bins supported (N <= 131072)
#define CAPB 8960        // per-bin edge capacity: mean E*128/N = 8192, sigma ~90 => +8.5 sigma
#define CHB 16384        // edges per binning block (391 blocks > 256 CUs)

__global__ void k_init(int* __restrict__ gcur, int B) {
    int t = blockIdx.x * blockDim.x + threadIdx.x;
    if (t < B) gcur[t] = t * CAPB;
}

// Chunked binning: LDS histogram -> one global reservation atomic per (block,bin) ->
// scatter packed edges. Per-(block,bin) runs are contiguous (~21 edges); the write
// frontier (2 lines/bin, block-owned, ~100KB working set) is L2-resident so lines
// fill before write-back. Pass-2 global re-read of src/dst is L2-warm (own chunk).
__global__ void __launch_bounds__(512) k_bin(const int* __restrict__ src, const int* __restrict__ dst,
                                             int* __restrict__ gcur, int* __restrict__ binned,
                                             int E, int B) {
    __shared__ int hist[NBMAX];
    __shared__ int base[NBMAX];
    int tid = threadIdx.x;
    int e0 = blockIdx.x * CHB;
    int n = E - e0; if (n > CHB) n = CHB;
    for (int t = tid; t < B; t += 512) hist[t] = 0;
    __syncthreads();
    for (int k = tid; k < n; k += 512) atomicAdd(&hist[dst[e0 + k] >> RSH], 1);
    __syncthreads();
    for (int t = tid; t < B; t += 512) {
        int h = hist[t];
        base[t] = h ? atomicAdd(&gcur[t], h) : 0;
        hist[t] = 0;  // reuse as local cursor
    }
    __syncthreads();
    for (int k = tid; k < n; k += 512) {
        int d = dst[e0 + k], s = src[e0 + k];
        int b = d >> RSH;
        int pos = base[b] + atomicAdd(&hist[b], 1);
        if (pos < (b + 1) * CAPB)  // overflow guard (deterministic input, 8.5-sigma slack)
            binned[pos] = ((d & (RNB - 1)) << 17) | s;  // src < 2^17
    }
}

// Per-bin fused: 1st read of bin -> deg histogram -> wave-shuffle exclusive scan ->
// offS/offE + dinv + xs=x*dinv -> 2nd read scatters into LDS buf sorted -> coalesced
// writeback (binned becomes src-only, node-sorted CSR). Single CAPB buffer (~37KB).
__global__ void __launch_bounds__(256) k_degsort(const int* __restrict__ gcur, int* __restrict__ binned,
                                                 const float* __restrict__ x, float* __restrict__ dinv,
                                                 float* __restrict__ xs, int* __restrict__ offS,
                                                 int* __restrict__ offE, int N) {
    __shared__ int buf[CAPB];
    __shared__ int deg[RNB];
    __shared__ int cur[RNB];
    __shared__ int wtot[2];
    int tid = threadIdx.x, b = blockIdx.x;
    int beg = b * CAPB;
    int end = gcur[b]; int cap = beg + CAPB; if (end > cap) end = cap;
    int cnt = end - beg;
    if (tid < RNB) deg[tid] = 0;
    __syncthreads();
    for (int k = tid; k < cnt; k += 256)
        atomicAdd(&deg[binned[beg + k] >> 17], 1);
    __syncthreads();
    int lane = tid & 63;
    int v = 0, incl = 0;
    if (tid < RNB) {
        v = deg[tid];
        incl = v;
#pragma unroll
        for (int d = 1; d < 64; d <<= 1) {
            int t = __shfl_up(incl, d);
            if (lane >= d) incl += t;
        }
        if (lane == 63) wtot[tid >> 6] = incl;
    }
    __syncthreads();
    if (tid < RNB) {
        int excl = ((tid >= 64) ? wtot[0] : 0) + incl - v;
        cur[tid] = excl;  // LDS-local cursor
        int i = b * RNB + tid;
        if (i < N) {
            offS[i] = beg + excl;
            offE[i] = beg + excl + v;
            float dv = rsqrtf((float)v + 1.0f);
            dinv[i] = dv;
            float2 xv = *reinterpret_cast<const float2*>(x + 2 * (size_t)i);
            float2 o; o.x = xv.x * dv; o.y = xv.y * dv;
            *reinterpret_cast<float2*>(xs + 2 * (size_t)i) = o;
        }
    }
    __syncthreads();
    for (int k = tid; k < cnt; k += 256) {  // 2nd read: L2-warm (just read above)
        int p = binned[beg + k];
        int pos = atomicAdd(&cur[p >> 17], 1);
        buf[pos] = p & 0x1FFFF;  // sorted, src-only
    }
    __syncthreads();
    for (int k = tid; k < cnt; k += 256)  // coalesced writeback (full lines)
        binned[beg + k] = buf[k];
}

// Wave-per-node gather: agg of xs (2 feats) -> z -> h1=relu(z@W1+b1) -> h2lin=h1@W2,
// h2s=h2lin*dinv. xs is 800KB => L2-resident gathers.
__global__ void k_l1(const int* __restrict__ offS, const int* __restrict__ offE,
                     const int* __restrict__ csr, const float* __restrict__ xs,
                     const float* __restrict__ x, const float* __restrict__ dinv,
                     const float* __restrict__ W1, const float* __restrict__ b1,
                     const float* __restrict__ W2,
                     float* __restrict__ h2lin, float* __restrict__ h2s, int N) {
    int gid = blockIdx.x * blockDim.x + threadIdx.x;
    int i = gid >> 6, lane = gid & 63;
    if (i >= N) return;
    int beg = offS[i], end = offE[i];
    float a0 = 0.f, a1 = 0.f;
    for (int e = beg + lane; e < end; e += 64) {
        int s = csr[e];
        float2 v = *reinterpret_cast<const float2*>(xs + 2 * (size_t)s);
        a0 += v.x; a1 += v.y;
    }
#pragma unroll
    for (int d = 32; d > 0; d >>= 1) { a0 += __shfl_xor(a0, d); a1 += __shfl_xor(a1, d); }
    if (lane == 0) {
        float dv = dinv[i], dv2 = dv * dv;
        float z0 = dv * a0 + x[2 * (size_t)i] * dv2;
        float z1 = dv * a1 + x[2 * (size_t)i + 1] * dv2;
        float acc[8];
#pragma unroll
        for (int g = 0; g < 8; ++g) acc[g] = 0.f;
#pragma unroll
        for (int f = 0; f < 16; ++f) {
            float h = fmaf(z0, W1[f], fmaf(z1, W1[16 + f], b1[f]));  // W1 [2,16] row-major
            h = fmaxf(h, 0.f);
#pragma unroll
            for (int g = 0; g < 8; ++g) acc[g] = fmaf(h, W2[f * 8 + g], acc[g]);
        }
        float4* o = reinterpret_cast<float4*>(h2lin + 8 * (size_t)i);
        o[0] = make_float4(acc[0], acc[1], acc[2], acc[3]);
        o[1] = make_float4(acc[4], acc[5], acc[6], acc[7]);
        float4* o2 = reinterpret_cast<float4*>(h2s + 8 * (size_t)i);
        o2[0] = make_float4(acc[0] * dv, acc[1] * dv, acc[2] * dv, acc[3] * dv);
        o2[1] = make_float4(acc[4] * dv, acc[5] * dv, acc[6] * dv, acc[7] * dv);
    }
}

// Fused layer-2 gather + final GEMM. Block = 8 nodes, 4 waves.
// Phase A: wave w gathers h2s neighbors for nodes 2w, 2w+1 (shuffle reduce), lane 0
// finishes zfin into LDS. Phase B: thread t computes out cols 4t..4t+3 for all 8 nodes.
// Eliminates the zfin global roundtrip.
__global__ void __launch_bounds__(256) k_l2f(const int* __restrict__ offS, const int* __restrict__ offE,
                                             const int* __restrict__ csr, const float* __restrict__ h2s,
                                             const float* __restrict__ h2lin, const float* __restrict__ dinv,
                                             const float* __restrict__ b2, const float* __restrict__ Wfc,
                                             const float* __restrict__ bfc, float* __restrict__ out,
                                             int N, int C) {
    __shared__ float sh[64];
    int i0 = blockIdx.x * 8;
    int tid = threadIdx.x, wid = tid >> 6, lane = tid & 63;
#pragma unroll
    for (int u = 0; u < 2; ++u) {
        int k = 2 * wid + u;
        int i = i0 + k;
        if (i < N) {
            int beg = offS[i], end = offE[i];
            float a[8];
#pragma unroll
            for (int g = 0; g < 8; ++g) a[g] = 0.f;
            for (int e = beg + lane; e < end; e += 64) {
                int s = csr[e];
                const float4* p = reinterpret_cast<const float4*>(h2s + 8 * (size_t)s);
                float4 u4 = p[0], w4 = p[1];
                a[0] += u4.x; a[1] += u4.y; a[2] += u4.z; a[3] += u4.w;
                a[4] += w4.x; a[5] += w4.y; a[6] += w4.z; a[7] += w4.w;
            }
#pragma unroll
            for (int g = 0; g < 8; ++g) {
#pragma unroll
                for (int d = 32; d > 0; d >>= 1) a[g] += __shfl_xor(a[g], d);
            }
            if (lane == 0) {
                float dv = dinv[i], dv2 = dv * dv;
                const float4* hl = reinterpret_cast<const float4*>(h2lin + 8 * (size_t)i);
                float4 h0 = hl[0], h1v = hl[1];
                sh[k * 8 + 0] = dv * a[0] + h0.x * dv2 + b2[0];
                sh[k * 8 + 1] = dv * a[1] + h0.y * dv2 + b2[1];
                sh[k * 8 + 2] = dv * a[2] + h0.z * dv2 + b2[2];
                sh[k * 8 + 3] = dv * a[3] + h0.w * dv2 + b2[3];
                sh[k * 8 + 4] = dv * a[4] + h1v.x * dv2 + b2[4];
                sh[k * 8 + 5] = dv * a[5] + h1v.y * dv2 + b2[5];
                sh[k * 8 + 6] = dv * a[6] + h1v.z * dv2 + b2[6];
                sh[k * 8 + 7] = dv * a[7] + h1v.w * dv2 + b2[7];
            }
        }
    }
    __syncthreads();
    int c4 = tid * 4;
    if (c4 + 4 <= C) {
        float4 w[8];
#pragma unroll
        for (int f = 0; f < 8; ++f)
            w[f] = *reinterpret_cast<const float4*>(Wfc + (size_t)f * C + c4);
        float4 bias = *reinterpret_cast<const float4*>(bfc + c4);
#pragma unroll 1
        for (int k = 0; k < 8; ++k) {
            int i = i0 + k;
            if (i >= N) break;
            float4 acc = bias;
#pragma unroll
            for (int f = 0; f < 8; ++f) {
                float hv = sh[k * 8 + f];
                acc.x = fmaf(hv, w[f].x, acc.x);
                acc.y = fmaf(hv, w[f].y, acc.y);
                acc.z = fmaf(hv, w[f].z, acc.z);
                acc.w = fmaf(hv, w[f].w, acc.w);
            }
            *reinterpret_cast<float4*>(out + (size_t)i * C + c4) = acc;
        }
    }
}

extern "C" void kernel_launch(void* const* d_in, const int* in_sizes, int n_in,
                              void* d_out, int out_size, void* d_ws, size_t ws_size,
                              hipStream_t stream) {
    const float* x   = (const float*)d_in[0];
    const int*   ei  = (const int*)d_in[1];
    const float* W1  = (const float*)d_in[2];
    const float* b1  = (const float*)d_in[3];
    const float* W2  = (const float*)d_in[4];
    const float* b2  = (const float*)d_in[5];
    const float* Wfc = (const float*)d_in[6];
    const float* bfc = (const float*)d_in[7];
    float* out = (float*)d_out;

    const int N = in_sizes[0] / 2;  // x is [N,2]
    const int E = in_sizes[1] / 2;  // edge_index is [2,E]
    const int C = in_sizes[7];      // bfc is [C]
    const int* src = ei;
    const int* dst = ei + E;

    const int B = (N + RNB - 1) >> RSH;  // bins (782 for N=100000)

    // ws layout (64B-aligned regions)
    size_t NP = (size_t)((N + 16) & ~15);
    int* gcur   = (int*)d_ws;                         // [NBMAX]
    int* binned = gcur + NBMAX;                       // [B*CAPB]; packed, then sorted src-only
    int* offS   = binned + (size_t)B * CAPB;          // [NP]
    int* offE   = offS + NP;                          // [NP]
    float* fb    = (float*)(offE + NP);
    float* dinv  = fb;              // [NP]
    float* xs    = dinv + NP;       // [2*NP]
    float* h2lin = xs + 2 * NP;     // [8*NP]
    float* h2s   = h2lin + 8 * NP;  // [8*NP]

    k_init<<<(B + 255) / 256, 256, 0, stream>>>(gcur, B);
    k_bin<<<(E + CHB - 1) / CHB, 512, 0, stream>>>(src, dst, gcur, binned, E, B);
    k_degsort<<<B, 256, 0, stream>>>(gcur, binned, x, dinv, xs, offS, offE, N);
    {
        long long tot = (long long)N * 64;  // one wave per node
        k_l1<<<(int)((tot + 255) / 256), 256, 0, stream>>>(offS, offE, binned, xs, x, dinv,
                                                           W1, b1, W2, h2lin, h2s, N);
    }
    k_l2f<<<(N + 7) / 8, 256, 0, stream>>>(offS, offE, binned, h2s, h2lin, dinv, b2,
                                           Wfc, bfc, out, N, C);
}